// Round 13
// baseline (196.209 us; speedup 1.0000x reference)
//
#include <hip/hip_runtime.h>

// etp: out[n, coff(l3)+m3, u] = sum_p sum_{m1,m2} cg_p[m1,m2,m3] * Y[n, yoff(l1)+m1]
//                               * H[n, coff(l2)+m2, u] * W[n, p, u]
// N=16384 edges, 16 ch (l=0..3, dims 1,3,5,7), MUL=128.
//
// R12: two-kernel split. K1 builds B_p[m3][m2]=sum_a cg*y for all edges into
// d_ws, packed: rows with d2<=4 take 1 float4 slot, d2>4 take 2 (158 f4 =
// 2528B/edge, padded 2560B; 42MB total, L2/L3-resident). K2 has NO LDS and
// no barriers: B comes in via wave-uniform global dwordx4 broadcasts (1
// transaction each, deep outstanding queue) while h/w stream coalesced.
// R0-R11 showed the LDS-broadcast pipe + exposed latency is the wall
// (dur identical whether HBM moved 298MB or 164MB); this removes the LDS
// pipe and lets VGPR-only occupancy hide VMEM latency.

#define BS 256
#define EPB 4     // edges per block (one wave each), both kernels
#define TPE 64
#define YD 16
#define HD 2048
#define WD 2944
#define BF4 160               // padded f4 slots per edge in Bws
#define BFLOAT (BF4 * 4)      // 640 floats per edge
#define WS_NEED ((size_t)16384 * BFLOAT * 4)

typedef float f2 __attribute__((ext_vector_type(2)));
typedef float f4 __attribute__((ext_vector_type(4)));

// X(p, l1, l2, l3, cg_offset, ro4) ; ro4 = packed f4 offset of row 0.
// row stride = 1 f4 if d2<=4 else 2 f4.
#define FOR_PATHS(X) \
  X(0, 0,0,0,    0,   0) \
  X(1, 0,1,1,    1,   1) \
  X(2, 0,2,2,   10,   4) \
  X(3, 0,3,3,   35,  14) \
  X(4, 1,0,1,   84,  28) \
  X(5, 1,1,0,   93,  31) \
  X(6, 1,1,2,  102,  32) \
  X(7, 1,2,1,  147,  37) \
  X(8, 1,2,3,  192,  43) \
  X(9, 1,3,2,  297,  57) \
  X(10,2,0,2,  402,  67) \
  X(11,2,1,1,  427,  72) \
  X(12,2,1,3,  472,  75) \
  X(13,2,2,0,  577,  82) \
  X(14,2,2,2,  602,  84) \
  X(15,2,3,1,  727,  94) \
  X(16,2,3,3,  832, 100) \
  X(17,3,0,3, 1077, 114) \
  X(18,3,1,2, 1126, 121) \
  X(19,3,2,1, 1231, 126) \
  X(20,3,2,3, 1336, 132) \
  X(21,3,3,0, 1581, 146) \
  X(22,3,3,2, 1630, 148)

__host__ __device__ constexpr int coff(int l) {
  return l == 0 ? 0 : (l == 1 ? 1 : (l == 2 ? 4 : 9));
}

// ---------------- Kernel 1: build packed B into d_ws ----------------
__global__ __launch_bounds__(BS) void build_kernel(
    const float* __restrict__ Y, const float* __restrict__ CG,
    float* __restrict__ Bws) {
  const int wid = threadIdx.x >> 6;
  const int l = threadIdx.x & 63;
  const size_t n = (size_t)blockIdx.x * EPB + wid;

  // Unconditional y broadcast (all 64 lanes active; R7-verified pattern).
  float yv = Y[n * YD + (l & 15)];
  float yy[YD];
#pragma unroll
  for (int c = 0; c < YD; ++c) yy[c] = __shfl(yv, c, 64);

  float* B = Bws + n * BFLOAT;
#define BLD(P, L1, L2, L3, CGO, RO4) { \
    constexpr int d1 = 2*(L1)+1, d2 = 2*(L2)+1, d3 = 2*(L3)+1; \
    constexpr int rs = (d2 > 4) ? 2 : 1; \
    if (l < d2 * d3) { \
      const int m3 = l / d2, m2 = l - m3 * d2; \
      float s = 0.f; \
      _Pragma("unroll") \
      for (int a = 0; a < d1; ++a) \
        s += CG[(CGO) + (a * d2 + m2) * d3 + m3] * yy[coff(L1) + a]; \
      B[((RO4) + m3 * rs) * 4 + m2] = s; \
    } }
  FOR_PATHS(BLD)
#undef BLD
}

// ---------------- Kernel 2: streaming contraction, no LDS ----------------
__global__ __launch_bounds__(BS, 4) void etp_kernel(
    const float* __restrict__ H, const float* __restrict__ W,
    const float* __restrict__ Bws, float* __restrict__ O) {
  const int g = threadIdx.x >> 6;
  const int l = threadIdx.x & 63;   // owns u = 2l, 2l+1
  const size_t n = (size_t)blockIdx.x * EPB + g;

  const f4* __restrict__ Bp = (const f4*)(Bws + n * BFLOAT);
  const f2* __restrict__ Hp = (const f2*)(H + n * HD);
  const f2* __restrict__ Wp = (const f2*)(W + n * WD);
  f2* __restrict__ Op = (f2*)(O + n * HD);

  f2 acc[YD];
#pragma unroll
  for (int c = 0; c < YD; ++c) acc[c] = (f2)0.f;

#define DOP(P, L2, L3, RO4) { \
    constexpr int d2 = 2*(L2)+1, d3 = 2*(L3)+1; \
    constexpr int rs = (d2 > 4) ? 2 : 1; \
    const f2 wv = Wp[(P) * TPE + l]; \
    _Pragma("unroll") \
    for (int m3 = 0; m3 < d3; ++m3) { \
      float br[8]; \
      *(f4*)&br[0] = Bp[(RO4) + m3 * rs]; \
      if (d2 > 4) *(f4*)&br[4] = Bp[(RO4) + m3 * rs + 1]; \
      f2 s = (f2)0.f; \
      _Pragma("unroll") \
      for (int m2 = 0; m2 < d2; ++m2) s += br[m2] * hh[m2]; \
      acc[coff(L3) + m3] += s * wv; \
    } }

  { // l2 = 0: paths 0,4,10,17
    f2 hh[1];
    hh[0] = Hp[(coff(0) + 0) * TPE + l];
    DOP(0, 0, 0, 0)  DOP(4, 0, 1, 28)  DOP(10, 0, 2, 67)  DOP(17, 0, 3, 114)
  }
  { // l2 = 1: paths 1,5,6,11,12,18
    f2 hh[3];
#pragma unroll
    for (int m = 0; m < 3; ++m) hh[m] = Hp[(coff(1) + m) * TPE + l];
    DOP(1, 1, 1, 1)  DOP(5, 1, 0, 31)  DOP(6, 1, 2, 32)
    DOP(11, 1, 1, 72)  DOP(12, 1, 3, 75)  DOP(18, 1, 2, 121)
  }
  { // l2 = 2: paths 2,7,8,13,14,19,20
    f2 hh[5];
#pragma unroll
    for (int m = 0; m < 5; ++m) hh[m] = Hp[(coff(2) + m) * TPE + l];
    DOP(2, 2, 2, 4)  DOP(7, 2, 1, 37)  DOP(8, 2, 3, 43)
    DOP(13, 2, 0, 82)  DOP(14, 2, 2, 84)  DOP(19, 2, 1, 126)  DOP(20, 2, 3, 132)
  }
  { // l2 = 3: paths 3,9,15,16,21,22
    f2 hh[7];
#pragma unroll
    for (int m = 0; m < 7; ++m) hh[m] = Hp[(coff(3) + m) * TPE + l];
    DOP(3, 3, 3, 14)  DOP(9, 3, 2, 57)  DOP(15, 3, 1, 94)
    DOP(16, 3, 3, 100)  DOP(21, 3, 0, 146)  DOP(22, 3, 2, 148)
  }
#undef DOP

#pragma unroll
  for (int c = 0; c < YD; ++c)
    __builtin_nontemporal_store(acc[c], &Op[c * TPE + l]);
}

// ---------------- Fallback (R11 single-kernel) if d_ws too small ----------
#define NROW 99
__global__ __launch_bounds__(BS, 4) void etp_fallback(
    const float* __restrict__ Y, const float* __restrict__ H,
    const float* __restrict__ W, const float* __restrict__ CG,
    float* __restrict__ O) {
  const int g = threadIdx.x >> 6;
  const int l = threadIdx.x & 63;
  const size_t n = (size_t)blockIdx.x * EPB + g;
  __shared__ __align__(16) float Bsm[EPB][NROW * 8];
  __shared__ float ysm[EPB][YD];
  { const int t = threadIdx.x;
    if (t < EPB * YD) {
      const int e = t >> 4, c = t & 15;
      ysm[e][c] = Y[(size_t)(blockIdx.x * EPB + e) * YD + c];
    } }
  __syncthreads();
  // old row offsets (stride 8 floats)
#define FOR_PATHS_OLD(X) \
  X(0,0,0,0,0,0) X(1,0,1,1,1,1) X(2,0,2,2,10,4) X(3,0,3,3,35,9) \
  X(4,1,0,1,84,16) X(5,1,1,0,93,19) X(6,1,1,2,102,20) X(7,1,2,1,147,25) \
  X(8,1,2,3,192,28) X(9,1,3,2,297,35) X(10,2,0,2,402,40) X(11,2,1,1,427,45) \
  X(12,2,1,3,472,48) X(13,2,2,0,577,55) X(14,2,2,2,602,56) X(15,2,3,1,727,61) \
  X(16,2,3,3,832,64) X(17,3,0,3,1077,71) X(18,3,1,2,1126,78) X(19,3,2,1,1231,83) \
  X(20,3,2,3,1336,86) X(21,3,3,0,1581,93) X(22,3,3,2,1630,94)
#define BUILD(P, L1, L2, L3, CGO, RO) { \
    constexpr int d1 = 2*(L1)+1, d2 = 2*(L2)+1, d3 = 2*(L3)+1; \
    if (l < d2 * d3) { \
      const int m3 = l / d2, m2 = l - m3 * d2; \
      float s = 0.f; \
      _Pragma("unroll") \
      for (int a = 0; a < d1; ++a) \
        s += CG[(CGO) + (a * d2 + m2) * d3 + m3] * ysm[g][coff(L1) + a]; \
      Bsm[g][((RO) + m3) * 8 + m2] = s; \
    } }
  FOR_PATHS_OLD(BUILD)
#undef BUILD
  __syncthreads();
  const f2* __restrict__ Hp = (const f2*)(H + n * HD);
  const f2* __restrict__ Wp = (const f2*)(W + n * WD);
  f2* __restrict__ Op = (f2*)(O + n * HD);
  f2 acc[YD];
#pragma unroll
  for (int c = 0; c < YD; ++c) acc[c] = (f2)0.f;
#define DOP(P, L2, L3, RO) { \
    constexpr int d2 = 2*(L2)+1, d3 = 2*(L3)+1; \
    const f2 wv = Wp[(P) * TPE + l]; \
    _Pragma("unroll") \
    for (int m3 = 0; m3 < d3; ++m3) { \
      const f4* row = (const f4*)&Bsm[g][((RO) + m3) * 8]; \
      float br[8]; \
      *(f4*)&br[0] = row[0]; \
      if (d2 > 4) *(f4*)&br[4] = row[1]; \
      f2 s = (f2)0.f; \
      _Pragma("unroll") \
      for (int m2 = 0; m2 < d2; ++m2) s += br[m2] * hh[m2]; \
      acc[coff(L3) + m3] += s * wv; \
    } }
  { f2 hh[1]; hh[0] = Hp[0 * TPE + l];
    DOP(0,0,0,0) DOP(4,0,1,16) DOP(10,0,2,40) DOP(17,0,3,71) }
  { f2 hh[3];
#pragma unroll
    for (int m = 0; m < 3; ++m) hh[m] = Hp[(1 + m) * TPE + l];
    DOP(1,1,1,1) DOP(5,1,0,19) DOP(6,1,2,20) DOP(11,1,1,45) DOP(12,1,3,48) DOP(18,1,2,78) }
  { f2 hh[5];
#pragma unroll
    for (int m = 0; m < 5; ++m) hh[m] = Hp[(4 + m) * TPE + l];
    DOP(2,2,2,4) DOP(7,2,1,25) DOP(8,2,3,28) DOP(13,2,0,55) DOP(14,2,2,56) DOP(19,2,1,83) DOP(20,2,3,86) }
  { f2 hh[7];
#pragma unroll
    for (int m = 0; m < 7; ++m) hh[m] = Hp[(9 + m) * TPE + l];
    DOP(3,3,3,9) DOP(9,3,2,35) DOP(15,3,1,61) DOP(16,3,3,64) DOP(21,3,0,93) DOP(22,3,2,94) }
#undef DOP
#pragma unroll
  for (int c = 0; c < YD; ++c)
    __builtin_nontemporal_store(acc[c], &Op[c * TPE + l]);
}

extern "C" void kernel_launch(void* const* d_in, const int* in_sizes, int n_in,
                              void* d_out, int out_size, void* d_ws, size_t ws_size,
                              hipStream_t stream) {
  const float* Y  = (const float*)d_in[0];
  const float* H  = (const float*)d_in[1];
  const float* W  = (const float*)d_in[2];
  const float* CG = (const float*)d_in[3];
  float* O = (float*)d_out;

  const int n_edges = in_sizes[0] / YD;        // 16384
  const int blocks = n_edges / EPB;            // 4096

  if (ws_size >= WS_NEED) {
    float* Bws = (float*)d_ws;
    build_kernel<<<blocks, BS, 0, stream>>>(Y, CG, Bws);
    etp_kernel<<<blocks, BS, 0, stream>>>(H, W, Bws, O);
  } else {
    etp_fallback<<<blocks, BS, 0, stream>>>(Y, H, W, CG, O);
  }
}

// Round 14
// 95.100 us; speedup vs baseline: 2.0632x; 2.0632x over previous
//
#include <hip/hip_runtime.h>

// etp: out[n, coff(l3)+m3, u] = sum_p sum_{m1,m2} cg_p[m1,m2,m3] * Y[n, yoff(l1)+m1]
//                               * H[n, coff(l2)+m2, u] * W[n, p, u]
// N=16384 edges, 16 ch (l=0..3, dims 1,3,5,7), MUL=128.
//
// R13 = R8 (champion: scalar u, 128 thr/edge, 2 edges/block, lean regs,
// high TLP) + ALL 39 global loads (h[16]+w[23]) hoisted into one pinned
// burst. Ledger R0-R12: dur tracks the 444MB working set through a
// ~4.3TB/s L3+HBM blend, best round = most waves; at-use w-loads throttle
// outstanding requests (1 exposure per path). Burst -> ~900 outstanding
// reqs/CU. asm pin stops the allocator sinking/remat (R1-R3 pathology);
// __launch_bounds__(256,6) caps at ~84 VGPR for the ~62-reg live set,
// 24 waves/CU.

#define BS 256
#define EPB 2     // edges per block
#define TPE 128   // threads per edge
#define YD 16
#define HD 2048
#define WD 2944
#define NP 23
#define NROW 99   // sum of d3 over paths (B rows, padded to 8 floats)

typedef float f4 __attribute__((ext_vector_type(4)));

// X(p, l1, l2, l3, cg_offset, row_offset)
#define FOR_PATHS(X) \
  X(0, 0,0,0,    0,  0) \
  X(1, 0,1,1,    1,  1) \
  X(2, 0,2,2,   10,  4) \
  X(3, 0,3,3,   35,  9) \
  X(4, 1,0,1,   84, 16) \
  X(5, 1,1,0,   93, 19) \
  X(6, 1,1,2,  102, 20) \
  X(7, 1,2,1,  147, 25) \
  X(8, 1,2,3,  192, 28) \
  X(9, 1,3,2,  297, 35) \
  X(10,2,0,2,  402, 40) \
  X(11,2,1,1,  427, 45) \
  X(12,2,1,3,  472, 48) \
  X(13,2,2,0,  577, 55) \
  X(14,2,2,2,  602, 56) \
  X(15,2,3,1,  727, 61) \
  X(16,2,3,3,  832, 64) \
  X(17,3,0,3, 1077, 71) \
  X(18,3,1,2, 1126, 78) \
  X(19,3,2,1, 1231, 83) \
  X(20,3,2,3, 1336, 86) \
  X(21,3,3,0, 1581, 93) \
  X(22,3,3,2, 1630, 94)

__host__ __device__ constexpr int coff(int l) {
  return l == 0 ? 0 : (l == 1 ? 1 : (l == 2 ? 4 : 9));
}

__global__ __launch_bounds__(BS, 6) void etp_kernel(
    const float* __restrict__ Y, const float* __restrict__ H,
    const float* __restrict__ W, const float* __restrict__ CG,
    float* __restrict__ O) {
  const int g = threadIdx.x >> 7;    // edge within block
  const int u = threadIdx.x & 127;   // u index
  const size_t n = (size_t)blockIdx.x * EPB + g;

  __shared__ __align__(16) float Bsm[EPB][NROW * 8];  // 6336 B
  __shared__ float ysm[EPB][YD];

  { const int t = threadIdx.x;
    if (t < EPB * YD) {
      const int e = t >> 4, c = t & 15;
      ysm[e][c] = Y[(size_t)(blockIdx.x * EPB + e) * YD + c];
    } }
  __syncthreads();

  // Phase 1: B_p[m3][m2] = sum_a cg_p[a,m2,m3] * y[coff(l1)+a], per edge.
#define BUILD(P, L1, L2, L3, CGO, RO) { \
    constexpr int d1 = 2*(L1)+1, d2 = 2*(L2)+1, d3 = 2*(L3)+1; \
    if (u < d2 * d3) { \
      const int m3 = u / d2, m2 = u - m3 * d2; \
      float s = 0.f; \
      _Pragma("unroll") \
      for (int a = 0; a < d1; ++a) \
        s += CG[(CGO) + (a * d2 + m2) * d3 + m3] * ysm[g][coff(L1) + a]; \
      Bsm[g][((RO) + m3) * 8 + m2] = s; \
    } }
  FOR_PATHS(BUILD)
#undef BUILD
  __syncthreads();

  // Phase 2: one burst of ALL 39 loads (pinned), then pure reg/LDS compute.
  const float* __restrict__ Hn = H + n * HD + u;
  const float* __restrict__ Wn = W + n * WD + u;
  float* __restrict__ On = O + n * HD + u;

  float h[YD];
#pragma unroll
  for (int c = 0; c < YD; ++c) h[c] = Hn[c * TPE];
  float w[NP];
#pragma unroll
  for (int p = 0; p < NP; ++p) w[p] = Wn[p * TPE];
  // Pin: forbid rematerialization/sinking of the burst.
#pragma unroll
  for (int c = 0; c < YD; ++c) asm volatile("" : "+v"(h[c]));
#pragma unroll
  for (int p = 0; p < NP; ++p) asm volatile("" : "+v"(w[p]));

  float acc[YD];
#pragma unroll
  for (int c = 0; c < YD; ++c) acc[c] = 0.f;

#define DOP(P, L1, L2, L3, CGO, RO) { \
    constexpr int d2 = 2*(L2)+1, d3 = 2*(L3)+1; \
    const float wv = w[P]; \
    _Pragma("unroll") \
    for (int m3 = 0; m3 < d3; ++m3) { \
      const f4* row = (const f4*)&Bsm[g][((RO) + m3) * 8]; \
      float br[8]; \
      *(f4*)&br[0] = row[0]; \
      if (d2 > 4) *(f4*)&br[4] = row[1]; \
      float s = 0.f; \
      _Pragma("unroll") \
      for (int m2 = 0; m2 < d2; ++m2) s += br[m2] * h[coff(L2) + m2]; \
      acc[coff(L3) + m3] += s * wv; \
    } }
  FOR_PATHS(DOP)
#undef DOP

#pragma unroll
  for (int c = 0; c < YD; ++c)
    __builtin_nontemporal_store(acc[c], &On[c * TPE]);
}

extern "C" void kernel_launch(void* const* d_in, const int* in_sizes, int n_in,
                              void* d_out, int out_size, void* d_ws, size_t ws_size,
                              hipStream_t stream) {
  const float* Y  = (const float*)d_in[0];
  const float* H  = (const float*)d_in[1];
  const float* W  = (const float*)d_in[2];
  const float* CG = (const float*)d_in[3];
  float* O = (float*)d_out;

  const int n_edges = in_sizes[0] / YD;        // 16384
  etp_kernel<<<n_edges / EPB, BS, 0, stream>>>(Y, H, W, CG, O);
}